// Round 1
// baseline (530.665 us; speedup 1.0000x reference)
//
#include <hip/hip_runtime.h>
#include <hip/hip_bf16.h>

#define NH 32
#define D_ 128
#define TT 16
#define B_ 4
#define T_ 4096

typedef short bf16x8 __attribute__((ext_vector_type(8)));
typedef float f32x4  __attribute__((ext_vector_type(4)));
typedef unsigned int u32;
typedef unsigned short u16;

__device__ __forceinline__ u16 f2bf(float f) {
    u32 x = __builtin_bit_cast(u32, f);
    u32 r = (x + 0x7FFFu + ((x >> 16) & 1u)) >> 16;
    return (u16)r;
}

// ---------------- K0: W[32][128i][128o] fp32 -> bf16 fragment-ordered ----------------
// W_f layout: [(h*8 + nt)*4 + kt][lane 0..63][8 bf16], element j of lane l =
//   W[h][ i = kt*32 + (l>>4)*8 + j ][ o = nt*16 + (l&15) ]
__global__ void k0_wprep(const float* __restrict__ W, uint4* __restrict__ Wf) {
    int gid  = blockIdx.x * blockDim.x + threadIdx.x; // 65536 threads
    int lane = gid & 63;
    int kt   = (gid >> 6) & 3;
    int nt   = (gid >> 8) & 7;
    int h    = gid >> 11;
    int o     = nt * 16 + (lane & 15);
    int ibase = kt * 32 + (lane >> 4) * 8;
    u16 v[8];
#pragma unroll
    for (int j = 0; j < 8; ++j)
        v[j] = f2bf(W[((size_t)h * D_ + (ibase + j)) * D_ + o]);
    uint4 o4;
    o4.x = (u32)v[0] | ((u32)v[1] << 16);
    o4.y = (u32)v[2] | ((u32)v[3] << 16);
    o4.z = (u32)v[4] | ((u32)v[5] << 16);
    o4.w = (u32)v[6] | ((u32)v[7] << 16);
    Wf[gid] = o4;
}

// ---------------- K1: mix1 (FWHT over heads) + per-head GEMM -> y (bf16) ----------------
// grid = tiles_in_chunk, block = 512. Tile = (b, 16 consecutive t).
// LDS slab: x_mixed bf16 [32h][16t][128i], byte addr = h*4096 + ((t*256 + i*2) ^ ((t&7)<<4))
__global__ __launch_bounds__(512, 1)
void k1_mix_gemm(const float* __restrict__ x, const uint4* __restrict__ Wf,
                 u16* __restrict__ y, int tile0) {
    __shared__ u16 slab[NH * TT * D_]; // 128 KiB
    char* sb = (char*)slab;

    int tile = tile0 + blockIdx.x;
    int b  = tile >> 8;           // 256 tiles per b
    int t0 = (tile & 255) * TT;
    int tid = threadIdx.x;

    // ---- staging + FWHT-32 over h ----
    {
        int iop  = tid & 63;      // i-pair: i = iop*2, iop*2+1
        int trow = tid >> 6;      // 0..7
#pragma unroll
        for (int pass = 0; pass < 2; ++pass) {
            int t = pass * 8 + trow;
            const float* src = x + ((size_t)(b * NH) * T_ + (t0 + t)) * D_ + iop * 2;
            float2 v[NH];
#pragma unroll
            for (int h = 0; h < NH; ++h)
                v[h] = *(const float2*)(src + (size_t)h * T_ * D_);
#pragma unroll
            for (int s = 1; s < NH; s <<= 1) {
#pragma unroll
                for (int j = 0; j < NH; ++j) {
                    if (j & s) continue;
                    float2 a = v[j], c = v[j + s];
                    v[j]     = make_float2(a.x + c.x, a.y + c.y);
                    v[j + s] = make_float2(a.x - c.x, a.y - c.y);
                }
            }
            u32 base = ((u32)(t * 256 + iop * 4)) ^ (((u32)t & 7u) << 4);
#pragma unroll
            for (int h = 0; h < NH; ++h) {
                u32 p = (u32)f2bf(v[h].x) | ((u32)f2bf(v[h].y) << 16);
                *(u32*)(sb + h * 4096 + base) = p;
            }
        }
    }
    __syncthreads();

    // ---- per-head 16x128 @ 128x128 GEMM via mfma_f32_16x16x32_bf16 ----
    int lane = tid & 63;
    int w    = tid >> 6;          // wave id -> o chunk [w*16, w*16+16)
    int ta   = lane & 15;         // A row (t)
    int kg   = lane >> 4;         // k group
    size_t ytile = (size_t)blockIdx.x * NH * TT * D_;

#pragma unroll 2
    for (int h = 0; h < NH; ++h) {
        f32x4 acc = {0.f, 0.f, 0.f, 0.f};
        const uint4* wfp = Wf + (((size_t)h * 8 + w) * 4) * 64 + lane;
#pragma unroll
        for (int kc = 0; kc < 4; ++kc) {
            u32 abyte = ((u32)(ta * 256 + (kc * 32 + kg * 8) * 2)) ^ (((u32)ta & 7u) << 4);
            bf16x8 a = *(const bf16x8*)(sb + h * 4096 + abyte);
            bf16x8 bb = __builtin_bit_cast(bf16x8, wfp[(size_t)kc * 64]);
            acc = __builtin_amdgcn_mfma_f32_16x16x32_bf16(a, bb, acc, 0, 0, 0);
        }
        int o = w * 16 + (lane & 15);
        size_t yb = ytile + (size_t)h * TT * D_;
#pragma unroll
        for (int r = 0; r < 4; ++r) {
            int t = kg * 4 + r;
            y[yb + t * D_ + o] = f2bf(acc[r]);
        }
    }
}

// ---------------- K2: mix2 (FWHT over heads) + beta scale -> out fp32 ----------------
// grid = tiles_in_chunk, block = 256; thread handles 4 t's of one o-pair.
__global__ __launch_bounds__(256, 1)
void k2_mix_beta(const u16* __restrict__ y, const float* __restrict__ beta,
                 float* __restrict__ out, int tile0) {
    int tile = tile0 + blockIdx.x;
    int b  = tile >> 8;
    int t0 = (tile & 255) * TT;
    int tid = threadIdx.x;
    int op = tid & 63;            // o-pair
    int tq = tid >> 6;            // 0..3

    float2 bv = *(const float2*)(beta + op * 2);
    float s0 = bv.x * (1.0f / 32.0f);
    float s1 = bv.y * (1.0f / 32.0f);

    const u16* yb = y + (size_t)blockIdx.x * NH * TT * D_;
#pragma unroll
    for (int ti = 0; ti < 4; ++ti) {
        int t = tq * 4 + ti;
        float2 v[NH];
#pragma unroll
        for (int h = 0; h < NH; ++h) {
            u32 p = *(const u32*)(yb + (h * TT + t) * D_ + op * 2);
            v[h].x = __builtin_bit_cast(float, p << 16);
            v[h].y = __builtin_bit_cast(float, p & 0xFFFF0000u);
        }
#pragma unroll
        for (int s = 1; s < NH; s <<= 1) {
#pragma unroll
            for (int j = 0; j < NH; ++j) {
                if (j & s) continue;
                float2 a = v[j], c = v[j + s];
                v[j]     = make_float2(a.x + c.x, a.y + c.y);
                v[j + s] = make_float2(a.x - c.x, a.y - c.y);
            }
        }
#pragma unroll
        for (int g = 0; g < NH; ++g) {
            float2 o2 = make_float2(v[g].x * s0, v[g].y * s1);
            *(float2*)(out + ((size_t)(b * NH + g) * T_ + (t0 + t)) * D_ + op * 2) = o2;
        }
    }
}

extern "C" void kernel_launch(void* const* d_in, const int* in_sizes, int n_in,
                              void* d_out, int out_size, void* d_ws, size_t ws_size,
                              hipStream_t stream) {
    const float* x    = (const float*)d_in[0];
    const float* W    = (const float*)d_in[1];
    const float* beta = (const float*)d_in[2];
    float* out = (float*)d_out;

    size_t wf_bytes = (size_t)NH * D_ * D_ * 2;           // 1 MiB
    uint4* Wf = (uint4*)d_ws;
    u16* ybuf = (u16*)((char*)d_ws + wf_bytes);
    size_t avail = (ws_size > wf_bytes) ? ws_size - wf_bytes : 0;

    const int total_tiles = B_ * (T_ / TT);               // 1024
    size_t per_tile = (size_t)NH * TT * D_ * 2;           // 128 KiB
    int tiles_per_chunk = (int)(avail / per_tile);
    if (tiles_per_chunk > total_tiles) tiles_per_chunk = total_tiles;
    if (tiles_per_chunk < 1) tiles_per_chunk = 1;

    k0_wprep<<<256, 256, 0, stream>>>(W, Wf);
    for (int t0 = 0; t0 < total_tiles; t0 += tiles_per_chunk) {
        int n = total_tiles - t0;
        if (n > tiles_per_chunk) n = tiles_per_chunk;
        k1_mix_gemm<<<n, 512, 0, stream>>>(x, Wf, ybuf, t0);
        k2_mix_beta<<<n, 256, 0, stream>>>(ybuf, beta, out, t0);
    }
}

// Round 3
// 477.424 us; speedup vs baseline: 1.1115x; 1.1115x over previous
//
#include <hip/hip_runtime.h>
#include <hip/hip_bf16.h>

#define NH 32
#define D_ 128
#define TT 16
#define B_ 4
#define T_ 4096

typedef short bf16x8 __attribute__((ext_vector_type(8)));
typedef float f32x4  __attribute__((ext_vector_type(4)));
typedef unsigned int u32;
typedef unsigned short u16;

__device__ __forceinline__ u16 f2bf(float f) {
    u32 x = __builtin_bit_cast(u32, f);
    u32 r = (x + 0x7FFFu + ((x >> 16) & 1u)) >> 16;
    return (u16)r;
}

// ---------------- K0: W[32][128i][128o] fp32 -> bf16 fragment-ordered ----------------
// W_f layout: [(h*8 + nt)*4 + kt][lane 0..63][8 bf16], element j of lane l =
//   W[h][ i = kt*32 + (l>>4)*8 + j ][ o = nt*16 + (l&15) ]
__global__ void k0_wprep(const float* __restrict__ W, uint4* __restrict__ Wf) {
    int gid  = blockIdx.x * blockDim.x + threadIdx.x; // 65536 threads
    int lane = gid & 63;
    int kt   = (gid >> 6) & 3;
    int nt   = (gid >> 8) & 7;
    int h    = gid >> 11;
    int o     = nt * 16 + (lane & 15);
    int ibase = kt * 32 + (lane >> 4) * 8;
    u16 v[8];
#pragma unroll
    for (int j = 0; j < 8; ++j)
        v[j] = f2bf(W[((size_t)h * D_ + (ibase + j)) * D_ + o]);
    uint4 o4;
    o4.x = (u32)v[0] | ((u32)v[1] << 16);
    o4.y = (u32)v[2] | ((u32)v[3] << 16);
    o4.z = (u32)v[4] | ((u32)v[5] << 16);
    o4.w = (u32)v[6] | ((u32)v[7] << 16);
    Wf[gid] = o4;
}

// ---------------- Fused: mix1 (FWHT) + per-head GEMM + mix2 (FWHT in regs) + beta ----
// grid = 1024 (one block per (b, 16-t tile)), block = 512 (8 waves, o-chunked).
// LDS slab: x_mixed bf16 [32h][16t][128i], byte addr = h*4096 + ((t*256 + i*2) ^ ((t&7)<<4))
__global__ __launch_bounds__(512, 2)
void k_fused(const float* __restrict__ x, const uint4* __restrict__ Wf,
             const float* __restrict__ beta, float* __restrict__ out) {
    __shared__ u16 slab[NH * TT * D_]; // 128 KiB
    char* sb = (char*)slab;

    int tile = blockIdx.x;
    int b  = tile >> 8;            // 256 tiles per b
    int t0 = (tile & 255) * TT;
    int tid = threadIdx.x;

    // ---- staging + FWHT-32 over h (float4 per thread: 32 lanes cover a 128-f row) ----
    {
        int ifour = tid & 31;      // i quad: i = ifour*4 .. +3
        int t     = tid >> 5;      // 0..15
        const float* src = x + ((size_t)(b * NH) * T_ + (t0 + t)) * D_ + ifour * 4;
        f32x4 v[NH];
#pragma unroll
        for (int h = 0; h < NH; ++h)
            v[h] = *(const f32x4*)(src + (size_t)h * T_ * D_);
#pragma unroll
        for (int s = 1; s < NH; s <<= 1) {
#pragma unroll
            for (int j = 0; j < NH; ++j) {
                if (j & s) continue;
                f32x4 a = v[j], c = v[j + s];
                v[j]     = a + c;
                v[j + s] = a - c;
            }
        }
        u32 base = ((u32)(t * 256 + ifour * 8)) ^ (((u32)t & 7u) << 4);
#pragma unroll
        for (int h = 0; h < NH; ++h) {
            uint2 p;
            p.x = (u32)f2bf(v[h][0]) | ((u32)f2bf(v[h][1]) << 16);
            p.y = (u32)f2bf(v[h][2]) | ((u32)f2bf(v[h][3]) << 16);
            *(uint2*)(sb + h * 4096 + base) = p;
        }
    }
    __syncthreads();

    // ---- per-head 16x128 @ 128x128 GEMM via mfma_f32_16x16x32_bf16, acc in regs ----
    int lane = tid & 63;
    int w    = tid >> 6;           // wave id -> o chunk [w*16, w*16+16)
    int ta   = lane & 15;          // A row (t) / D col (o low)
    int kg   = lane >> 4;          // k group / D row group

    f32x4 acc[NH];
#pragma unroll
    for (int h = 0; h < NH; ++h) acc[h] = f32x4{0.f, 0.f, 0.f, 0.f};

#pragma unroll
    for (int h = 0; h < NH; ++h) {
        const uint4* wfp = Wf + (((size_t)h * 8 + w) * 4) * 64 + lane;
#pragma unroll
        for (int kc = 0; kc < 4; ++kc) {
            u32 abyte = ((u32)(ta * 256 + (kc * 32 + kg * 8) * 2)) ^ (((u32)ta & 7u) << 4);
            bf16x8 a  = *(const bf16x8*)(sb + h * 4096 + abyte);
            bf16x8 bb = __builtin_bit_cast(bf16x8, wfp[(size_t)kc * 64]);
            acc[h] = __builtin_amdgcn_mfma_f32_16x16x32_bf16(a, bb, acc[h], 0, 0, 0);
        }
    }

    // ---- mix2: FWHT-32 over h, fully in registers ----
#pragma unroll
    for (int s = 1; s < NH; s <<= 1) {
#pragma unroll
        for (int j = 0; j < NH; ++j) {
            if (j & s) continue;
            f32x4 a = acc[j], c = acc[j + s];
            acc[j]     = a + c;
            acc[j + s] = a - c;
        }
    }

    // ---- beta scale + store fp32 ----
    int o = w * 16 + ta;
    float bv = beta[o] * (1.0f / 32.0f);
    float* op0 = out + ((size_t)b * NH * T_ + (t0 + kg * 4)) * D_ + o;
#pragma unroll
    for (int g = 0; g < NH; ++g) {
        float* og = op0 + (size_t)g * T_ * D_;
#pragma unroll
        for (int r = 0; r < 4; ++r)
            og[r * D_] = acc[g][r] * bv;
    }
}

extern "C" void kernel_launch(void* const* d_in, const int* in_sizes, int n_in,
                              void* d_out, int out_size, void* d_ws, size_t ws_size,
                              hipStream_t stream) {
    const float* x    = (const float*)d_in[0];
    const float* W    = (const float*)d_in[1];
    const float* beta = (const float*)d_in[2];
    float* out = (float*)d_out;

    uint4* Wf = (uint4*)d_ws;   // 1 MiB

    k0_wprep<<<256, 256, 0, stream>>>(W, Wf);
    k_fused<<<B_ * (T_ / TT), 512, 0, stream>>>(x, Wf, beta, out);
}